// Round 12
// baseline (2899.920 us; speedup 1.0000x reference)
//
#include <hip/hip_runtime.h>

// ---------------------------------------------------------------------------
// CUBA spiking CNN, forward only.
// Numerics contract (match a canonical numpy fp32 trajectory):
//   * every dot/conv = ONE fp32 accumulator per output, sequential fmaf
//     chain in ascending k-order ((c,i,j) for convs, 0..K-1 for matmuls)
//   * bias added AFTER the sum (reference association), unfused
//   * all elementwise/LIF ops unfused fp32 (__fmul_rn/__fadd_rn; no FMA
//     contraction — numpy ufuncs don't contract)
//   * spikes stored u8 (exact), pooled values exact multiples of 0.25
// R18:
//  * k_rec REVERTED to R16 (264us best; R17 bit-predication was 412us —
//    doubled the VALU dep-chain and weights still not resident).
//  * k_conv2: s1 staged as RAW U8 (8KB vs 32KB LDS); per c the 16
//    wave-uniform ds_read_b128 (192cy on the shared per-CU LDS pipe —
//    the actual limiter; VALU only 44% busy) become 8 uint2 byte-reads,
//    unpacked in-register via (float)((u>>8q)&0xff) (v_cvt_f32_ubyte).
//    u8{0,1}->float is exact; per-output fmaf chain order unchanged.
// ---------------------------------------------------------------------------

#define B_   64
#define T_   200
#define TCB_ 50

__device__ __forceinline__ void lif32(float psp, float& cur, float& volt, float& spk) {
#pragma clang fp contract(off)
    cur  = __fadd_rn(__fmul_rn(0.5f, cur), psp);
    volt = __fadd_rn(__fmul_rn(__fmul_rn(0.75f, volt), __fsub_rn(1.0f, spk)), cur);
    spk  = (volt > 0.5f) ? 1.0f : 0.0f;
}

// ---------------------------------------------------------------------------
// K0: weight transposes (fp32). dst[k*N+o] = src[o*K+k]
// ---------------------------------------------------------------------------
__global__ void k_setup(const float* __restrict__ w2, const float* __restrict__ w3,
                        const float* __restrict__ tcw, const float* __restrict__ recw,
                        const float* __restrict__ fw,
                        float* __restrict__ w2T, float* __restrict__ w3T,
                        float* __restrict__ tcT, float* __restrict__ recT,
                        float* __restrict__ fc1T) {
    int idx = blockIdx.x * 256 + threadIdx.x;
    if (idx < 73728) { int o = idx & 127, k = idx >> 7; w2T[idx] = w2[o * 576 + k]; return; }
    idx -= 73728;
    if (idx < 294912) { int o = idx & 255, k = idx >> 8; w3T[idx] = w3[o * 1152 + k]; return; }
    idx -= 294912;
    if (idx < 196608) { int tap = idx >> 16, r = idx & 65535; int o = r & 255, k = r >> 8;
                        tcT[idx] = tcw[tap * 65536 + o * 256 + k]; return; }
    idx -= 196608;
    if (idx < 65536) { int o = idx & 255, k = idx >> 8; recT[idx] = recw[o * 256 + k]; return; }
    idx -= 65536;
    if (idx < 32768) { int o = idx & 127, k = idx >> 7; fc1T[idx] = fw[o * 256 + k]; return; }
}

// ---------------------------------------------------------------------------
// K1: conv1 (1->64, 3x3, 10x10->8x8) + LIF1, one chunk. Sequential fp32
// fmaf over (i,j); psp = sum + bias (unfused). States fp32 in st1.
// ---------------------------------------------------------------------------
__global__ __launch_bounds__(256) void k_conv1(const float* __restrict__ x,
                                               const float* __restrict__ w1,
                                               const float* __restrict__ b1,
                                               unsigned char* __restrict__ s1c,
                                               float* __restrict__ st1,
                                               int t0, int TC, int first) {
    int idx = blockIdx.x * 256 + threadIdx.x;   // 262144
    int xx = idx & 7, yy = (idx >> 3) & 7, o = (idx >> 6) & 63, b = idx >> 12;
    float w[9];
#pragma unroll
    for (int i = 0; i < 9; i++) w[i] = w1[o * 9 + i];
    float bias = b1[o];
    const float* xb = x + (size_t)b * 20000;
    unsigned char* sb = s1c + (size_t)b * TC * 4096 + (o << 6) + (yy << 3) + xx;
    float cur, volt, spk;
    if (first) { cur = 0.f; volt = 0.f; spk = 0.f; }
    else { cur = st1[idx]; volt = st1[262144 + idx]; spk = st1[524288 + idx]; }
    for (int tl = 0; tl < TC; tl += 4) {
        int t = t0 + tl;
        float a0 = 0.f, a1 = 0.f, a2 = 0.f, a3 = 0.f;
#pragma unroll
        for (int i = 0; i < 3; i++) {
#pragma unroll
            for (int j = 0; j < 3; j++) {
                float4 v = *(const float4*)&xb[((yy + i) * 10 + xx + j) * T_ + t];
                float wv = w[i * 3 + j];
                a0 = fmaf(wv, v.x, a0); a1 = fmaf(wv, v.y, a1);
                a2 = fmaf(wv, v.z, a2); a3 = fmaf(wv, v.w, a3);
            }
        }
        float accs[4] = {a0, a1, a2, a3};
#pragma unroll
        for (int q = 0; q < 4; q++) {
            float psp = __fadd_rn(accs[q], bias);
            lif32(psp, cur, volt, spk);
            sb[(size_t)(tl + q) * 4096] = (unsigned char)spk;
        }
    }
    st1[idx] = cur; st1[262144 + idx] = volt; st1[524288 + idx] = spk;
}

// ---------------------------------------------------------------------------
// K2: conv2 (64->128, 3x3, 8x8->6x6), 2 timesteps per block, U8 staging
// (R18). grid = B * TC/2, 384 threads. Thread = (oc = tid&127, yg =
// tid>>7): rows {2yg,2yg+1} x 6x for ONE oc, both staged timesteps.
// s1 staged as raw u8 (8KB LDS); per c per half: 4 uint2 byte-row reads
// (wave-uniform broadcast) unpacked via (float)((u>>8q)&0xff) — exact for
// spike values {0,1}. Weight loads lane-consecutive in oc (coalesced),
// next-c prefetch. Stores coalesced (psp2c[b][t][y][x][oc]).
// Per output: sequential fmaf in (c,i,j) ascending order; +bias after.
// ---------------------------------------------------------------------------
__global__ __launch_bounds__(384) void k_conv2(const unsigned char* __restrict__ s1c,
                                               const float* __restrict__ w2T,
                                               const float* __restrict__ b2,
                                               float* __restrict__ psp2c, int TC) {
    __shared__ __align__(16) unsigned char s_u8[2][4096];
    int blk = blockIdx.x;                       // b*(TC/2) + tp
    int th = TC >> 1;
    int b = blk / th, tp = blk - b * th;
    int tl0 = 2 * tp;
    int tid = threadIdx.x;
#pragma unroll
    for (int h = 0; h < 2; h++) {
        const unsigned int* src4 = (const unsigned int*)(s1c + (size_t)(b * TC + tl0 + h) * 4096);
        unsigned int* dst4 = (unsigned int*)&s_u8[h][0];
        for (int i = tid; i < 1024; i += 384) dst4[i] = src4[i];
    }
    __syncthreads();
    int oc = tid & 127;
    int yg = tid >> 7;                          // 0..2 (wave-uniform)
    int y0 = 2 * yg;
    float a0[2][6], a1[2][6];                   // [t][x]
#pragma unroll
    for (int h = 0; h < 2; h++)
#pragma unroll
        for (int xq = 0; xq < 6; xq++) { a0[h][xq] = 0.f; a1[h][xq] = 0.f; }
    const float* wb = w2T + oc;
    float w[9];
#pragma unroll
    for (int q = 0; q < 9; q++) w[q] = wb[(size_t)q * 128];     // c = 0
    for (int c = 0; c < 64; c++) {
        // prefetch next c's weights (independent of this c's FMA block);
        // (c+1)&63 keeps the last prefetch in-bounds (value discarded)
        int cn = (c + 1) & 63;
        float wn[9];
#pragma unroll
        for (int q = 0; q < 9; q++) wn[q] = wb[(size_t)(cn * 9 + q) * 128];
#pragma unroll
        for (int h = 0; h < 2; h++) {
            const unsigned char* sc = &s_u8[h][c * 64 + y0 * 8];
            float row[4][8];                    // only one t's rows live
#pragma unroll
            for (int ry = 0; ry < 4; ry++) {
                uint2 uu = *(const uint2*)(sc + ry * 8);   // 8B-aligned byte row
#pragma unroll
                for (int q = 0; q < 4; q++) {
                    row[ry][q]     = (float)((uu.x >> (8 * q)) & 0xffu);
                    row[ry][4 + q] = (float)((uu.y >> (8 * q)) & 0xffu);
                }
            }
#pragma unroll
            for (int i = 0; i < 3; i++)
#pragma unroll
                for (int j = 0; j < 3; j++) {
                    float wv = w[i * 3 + j];
#pragma unroll
                    for (int xq = 0; xq < 6; xq++) {
                        a0[h][xq] = fmaf(wv, row[i][xq + j], a0[h][xq]);
                        a1[h][xq] = fmaf(wv, row[i + 1][xq + j], a1[h][xq]);
                    }
                }
        }
#pragma unroll
        for (int q = 0; q < 9; q++) w[q] = wn[q];
    }
    float bv = b2[oc];
#pragma unroll
    for (int h = 0; h < 2; h++) {
        float* base = psp2c + (size_t)(b * TC + tl0 + h) * 4608;
        float* d0 = base + (size_t)(y0 * 6) * 128 + oc;
        float* d1 = base + (size_t)((y0 + 1) * 6) * 128 + oc;
#pragma unroll
        for (int xq = 0; xq < 6; xq++) {
            d0[(size_t)xq * 128] = __fadd_rn(a0[h][xq], bv);
            d1[(size_t)xq * 128] = __fadd_rn(a1[h][xq], bv);
        }
    }
}

// ---------------------------------------------------------------------------
// K3: LIF2 + AvgPool(2), fp32 states (12 planes x 73728 in st2), chunk.
// psp2c layout [b][t][y][x][oc]; thread = (b, pos, oc), oc in low bits ->
// the 4 quad reads are lane-consecutive (coalesced). Quad order unchanged.
// pc: fp32 [b*TC+tl][oc*9+pos] (unchanged layout for conv3).
// ---------------------------------------------------------------------------
__global__ __launch_bounds__(256) void k_lif2pool(const float* __restrict__ psp2c,
                                                  float* __restrict__ pc,
                                                  float* __restrict__ st2,
                                                  int TC, int first) {
    int idx = blockIdx.x * 256 + threadIdx.x;   // 73728
    int oc = idx & 127;
    int r = idx >> 7;                           // b*9 + pos
    int pos = r % 9;
    int b = r / 9;
    int py = pos / 3, px = pos - py * 3;
    const float* pb = psp2c + (size_t)b * TC * 4608;
    int off00 = ((2 * py) * 6 + 2 * px) * 128 + oc;
    int off01 = ((2 * py) * 6 + 2 * px + 1) * 128 + oc;
    int off10 = ((2 * py + 1) * 6 + 2 * px) * 128 + oc;
    int off11 = ((2 * py + 1) * 6 + 2 * px + 1) * 128 + oc;
    float* pd = pc + (size_t)b * TC * 1152 + oc * 9 + pos;
    float c0, c1, c2, c3, v0, v1, v2, v3, s0, s1, s2, s3;
    if (first) {
        c0 = c1 = c2 = c3 = v0 = v1 = v2 = v3 = s0 = s1 = s2 = s3 = 0.f;
    } else {
        c0 = st2[idx];              c1 = st2[73728 + idx];
        c2 = st2[147456 + idx];     c3 = st2[221184 + idx];
        v0 = st2[294912 + idx];     v1 = st2[368640 + idx];
        v2 = st2[442368 + idx];     v3 = st2[516096 + idx];
        s0 = st2[589824 + idx];     s1 = st2[663552 + idx];
        s2 = st2[737280 + idx];     s3 = st2[811008 + idx];
    }
    for (int tl = 0; tl < TC; tl++) {
        const float* pt = pb + (size_t)tl * 4608;
        float p0 = pt[off00];
        float p1 = pt[off01];
        float p2 = pt[off10];
        float p3 = pt[off11];
        lif32(p0, c0, v0, s0);
        lif32(p1, c1, v1, s1);
        lif32(p2, c2, v2, s2);
        lif32(p3, c3, v3, s3);
        // sum of 0/1 values: exact in any order; *0.25 exact
        pd[(size_t)tl * 1152] = __fmul_rn(0.25f, __fadd_rn(__fadd_rn(__fadd_rn(s0, s1), s2), s3));
    }
    st2[idx] = c0;           st2[73728 + idx] = c1;
    st2[147456 + idx] = c2;  st2[221184 + idx] = c3;
    st2[294912 + idx] = v0;  st2[368640 + idx] = v1;
    st2[442368 + idx] = v2;  st2[516096 + idx] = v3;
    st2[589824 + idx] = s0;  st2[663552 + idx] = s1;
    st2[737280 + idx] = s2;  st2[811008 + idx] = s3;
}

// ---------------------------------------------------------------------------
// K4: conv3 GEMM, 4 rows x 256 outputs per block. Per output: sequential
// fp32 fmaf k=0..1151 ascending. Epilogue: +bias unfused.
// ---------------------------------------------------------------------------
__global__ __launch_bounds__(256) void k_conv3(const float* __restrict__ pc,
                                               const float* __restrict__ w3T,
                                               const float* __restrict__ b3,
                                               float* __restrict__ psp3c) {
    __shared__ float a_s[4 * 1152];
    int row0 = blockIdx.x * 4;
    int tid = threadIdx.x;
    int oq = tid & 63, mg = tid >> 6;           // 64 output-quads x 4 rows
    for (int idx = tid; idx < 4 * 1152; idx += 256) {
        int m = idx / 1152, k = idx - m * 1152;
        a_s[idx] = pc[(size_t)(row0 + m) * 1152 + k];
    }
    __syncthreads();
    float acc[4] = {0.f, 0.f, 0.f, 0.f};
    const float* as_row = &a_s[mg * 1152];      // wave-uniform -> broadcast reads
#pragma unroll 4
    for (int k = 0; k < 1152; k++) {
        float4 wv = *(const float4*)&w3T[(size_t)k * 256 + (oq << 2)];
        float am = as_row[k];
        acc[0] = fmaf(wv.x, am, acc[0]);
        acc[1] = fmaf(wv.y, am, acc[1]);
        acc[2] = fmaf(wv.z, am, acc[2]);
        acc[3] = fmaf(wv.w, am, acc[3]);
    }
    float* dst = psp3c + (size_t)(row0 + mg) * 256 + (oq << 2);
#pragma unroll
    for (int oo = 0; oo < 4; oo++)
        dst[oo] = __fadd_rn(acc[oo], b3[(oq << 2) + oo]);
}

// ---------------------------------------------------------------------------
// K5: LIF3 scan on chunk, fp32 states (st3), writes u8 s3u8[b][t][256].
// ---------------------------------------------------------------------------
__global__ __launch_bounds__(256) void k_scan3(const float* __restrict__ psp3c,
                                               unsigned char* __restrict__ s3u8,
                                               float* __restrict__ st3,
                                               int t0, int TC, int first) {
    int idx = blockIdx.x * 256 + threadIdx.x;   // 16384
    int b = idx >> 8, n = idx & 255;
    float cur, volt, spk;
    if (first) { cur = 0.f; volt = 0.f; spk = 0.f; }
    else { cur = st3[idx]; volt = st3[16384 + idx]; spk = st3[32768 + idx]; }
    for (int tl = 0; tl < TC; tl++) {
        lif32(psp3c[(size_t)(b * TC + tl) * 256 + n], cur, volt, spk);
        s3u8[((size_t)b * T_ + t0 + tl) * 256 + n] = (unsigned char)spk;
    }
    st3[idx] = cur; st3[16384 + idx] = volt; st3[32768 + idx] = spk;
}

// ---------------------------------------------------------------------------
// K6: temporal conv, back-end chunk TCB=50. Per tap: sequential fp32 dot
// (k=0..255) -> +bias (unfused) -> gated sequential psum (numpy order).
// ---------------------------------------------------------------------------
__global__ __launch_bounds__(256) void k_tc(const unsigned char* __restrict__ s3u8,
                                            const float* __restrict__ tcT,
                                            const float* __restrict__ tc_b,
                                            float* __restrict__ ptcc, int t0) {
    __shared__ float a_s[16 * 256];
    int crow0 = blockIdx.x * 16;
    int tid = threadIdx.x;
    int oq = tid & 63, mg = tid >> 6;
    float psum[4][4];
#pragma unroll
    for (int oo = 0; oo < 4; oo++)
#pragma unroll
        for (int mi = 0; mi < 4; mi++) psum[oo][mi] = 0.f;
    for (int tap = 0; tap < 3; tap++) {
        __syncthreads();
        for (int idx = tid; idx < 16 * 256; idx += 256) {
            int m = idx >> 8, k = idx & 255;
            int crow = crow0 + m;
            int b = crow / TCB_, tl = crow - b * TCB_;
            int t = t0 + tl;
            float v = 0.f;
            if (t >= tap) v = (float)s3u8[((size_t)b * T_ + t - tap) * 256 + k];
            a_s[idx] = v;
        }
        __syncthreads();
        float acc[4][4];
#pragma unroll
        for (int oo = 0; oo < 4; oo++)
#pragma unroll
            for (int mi = 0; mi < 4; mi++) acc[oo][mi] = 0.f;
        const float* wbase = tcT + (size_t)tap * 65536 + (oq << 2);
        for (int k = 0; k < 256; k++) {
            float4 wv = *(const float4*)(wbase + (size_t)k * 256);
            float w4[4] = {wv.x, wv.y, wv.z, wv.w};
            float am[4];
#pragma unroll
            for (int mi = 0; mi < 4; mi++) am[mi] = a_s[(mg * 4 + mi) * 256 + k];
#pragma unroll
            for (int oo = 0; oo < 4; oo++)
#pragma unroll
                for (int mi = 0; mi < 4; mi++)
                    acc[oo][mi] = fmaf(w4[oo], am[mi], acc[oo][mi]);
        }
#pragma unroll
        for (int mi = 0; mi < 4; mi++) {
            int crow = crow0 + mg * 4 + mi;
            int b = crow / TCB_, tl = crow - b * TCB_;
            int t = t0 + tl;
            float g = (t >= tap) ? 1.0f : 0.0f;
#pragma unroll
            for (int oo = 0; oo < 4; oo++) {
                int oc = (oq << 2) + oo;
                float tap_f = __fadd_rn(acc[oo][mi], tc_b[tap * 256 + oc]);
                psum[oo][mi] = __fadd_rn(psum[oo][mi], __fmul_rn(g, tap_f));
            }
        }
    }
#pragma unroll
    for (int mi = 0; mi < 4; mi++) {
        int crow = crow0 + mg * 4 + mi;
        float* dst = ptcc + (size_t)crow * 256 + (oq << 2);
#pragma unroll
        for (int oo = 0; oo < 4; oo++) dst[oo] = psum[oo][mi];
    }
}

// ---------------------------------------------------------------------------
// K7: LIF scan for tc layer, back-end chunk, fp32 states st_tc.
// ---------------------------------------------------------------------------
__global__ __launch_bounds__(256) void k_scan_tc(const float* __restrict__ ptcc,
                                                 unsigned char* __restrict__ s_tc8,
                                                 float* __restrict__ st_tc,
                                                 int t0, int first) {
    int idx = blockIdx.x * 256 + threadIdx.x;   // 16384
    int b = idx >> 8, n = idx & 255;
    float cur, volt, spk;
    if (first) { cur = 0.f; volt = 0.f; spk = 0.f; }
    else { cur = st_tc[idx]; volt = st_tc[16384 + idx]; spk = st_tc[32768 + idx]; }
    for (int tl = 0; tl < TCB_; tl++) {
        lif32(ptcc[(size_t)(b * TCB_ + tl) * 256 + n], cur, volt, spk);
        s_tc8[((size_t)b * T_ + t0 + tl) * 256 + n] = (unsigned char)spk;
    }
    st_tc[idx] = cur; st_tc[16384 + idx] = volt; st_tc[32768 + idx] = spk;
}

// ---------------------------------------------------------------------------
// K8: recurrent layer, split-chain, NAMED-float4 register weights +
// amdgpu_waves_per_eu(2,2) (R16 exact — measured 264us best).
// 512 threads/block, WG per batch element. Thread (o = tid&255,
// half = tid>>8) holds its 128-weight slice in 32 NAMED float4 variables.
// Per step:
//   half 0: acc = chain(0, k=0..127)          -> acc_s[o]
//   barrier
//   half 1: acc = chain(acc_s[o], k=128..255) -> +stc +rb -> LIF -> store,
//           publish spike to spk_s[p^1]
//   barrier
// chain(chain(0,k<128),k>=128) is the IDENTICAL fmaf sequence as the single
// 256-link chain -> bit-identical. fmaf(s,w,acc) with s in {0,1} is
// bit-identical to __fadd_rn(acc, s?w:0). Branches wave-uniform.
// ---------------------------------------------------------------------------
__global__ __launch_bounds__(512)
__attribute__((amdgpu_waves_per_eu(2, 2)))
void k_rec(const unsigned char* __restrict__ s_tc8,
           const float* __restrict__ rec_w,
           const float* __restrict__ rec_b,
           unsigned char* __restrict__ s_r8) {
    __shared__ __align__(16) float spk_s[2][256];
    __shared__ float acc_s[256];
    int b = blockIdx.x;
    int tid = threadIdx.x;
    int o = tid & 255, half = tid >> 8;
    const float* wrow = rec_w + (size_t)o * 256 + (half << 7);
#define WD(i) float4 w##i = *(const float4*)&wrow[4 * i];
    WD(0)  WD(1)  WD(2)  WD(3)  WD(4)  WD(5)  WD(6)  WD(7)
    WD(8)  WD(9)  WD(10) WD(11) WD(12) WD(13) WD(14) WD(15)
    WD(16) WD(17) WD(18) WD(19) WD(20) WD(21) WD(22) WD(23)
    WD(24) WD(25) WD(26) WD(27) WD(28) WD(29) WD(30) WD(31)
#undef WD
    if (half == 0) spk_s[0][o] = 0.f;
    float cur = 0.f, volt = 0.f, spk = 0.f;
    float rb = rec_b[o];
    const unsigned char* stp = s_tc8 + (size_t)b * T_ * 256 + o;
    unsigned char* srp = s_r8 + (size_t)b * T_ * 256 + o;
    __syncthreads();
    int p = 0;
    // CH(i): 4 chain links using float4 i (ascending k within the slice)
#define CH(i, sp) { float4 sv = *(const float4*)&(sp)[4 * i]; \
        acc = fmaf(sv.x, w##i.x, acc); acc = fmaf(sv.y, w##i.y, acc); \
        acc = fmaf(sv.z, w##i.z, acc); acc = fmaf(sv.w, w##i.w, acc); }
#define CHAIN32(sp) \
    CH(0,sp)  CH(1,sp)  CH(2,sp)  CH(3,sp)  CH(4,sp)  CH(5,sp)  CH(6,sp)  CH(7,sp) \
    CH(8,sp)  CH(9,sp)  CH(10,sp) CH(11,sp) CH(12,sp) CH(13,sp) CH(14,sp) CH(15,sp) \
    CH(16,sp) CH(17,sp) CH(18,sp) CH(19,sp) CH(20,sp) CH(21,sp) CH(22,sp) CH(23,sp) \
    CH(24,sp) CH(25,sp) CH(26,sp) CH(27,sp) CH(28,sp) CH(29,sp) CH(30,sp) CH(31,sp)
    for (int t = 0; t < T_; t++) {
        if (half == 0) {
            const float* sp = spk_s[p];
            float acc = 0.f;
            CHAIN32(sp)
            acc_s[o] = acc;
        }
        __syncthreads();                // publish partial acc
        if (half == 1) {
            float stc = (float)stp[(size_t)t * 256];   // independent, issues early
            const float* sp = spk_s[p] + 128;
            float acc = acc_s[o];
            CHAIN32(sp)
            float psp = __fadd_rn(__fadd_rn(stc, acc), rb);
            lif32(psp, cur, volt, spk);
            srp[(size_t)t * 256] = (unsigned char)spk;
            spk_s[p ^ 1][o] = spk;      // publish spike for next step
        }
        __syncthreads();
        p ^= 1;
    }
#undef CH
#undef CHAIN32
}

// ---------------------------------------------------------------------------
// K9: fc1 GEMM, back-end chunk. Sequential fp32 fmaf k=0..255; +bias after.
// ---------------------------------------------------------------------------
__global__ __launch_bounds__(256) void k_fc1(const unsigned char* __restrict__ s_r8,
                                             const float* __restrict__ fc1T,
                                             const float* __restrict__ fc1_b,
                                             float* __restrict__ pfc, int t0) {
    __shared__ float a_s[16 * 256];
    int crow0 = blockIdx.x * 16;
    int tid = threadIdx.x;
    int oq = tid & 31, mg = tid >> 5;           // 8 m-groups, tile 2m
    float acc[4][2];
#pragma unroll
    for (int oo = 0; oo < 4; oo++) { acc[oo][0] = 0.f; acc[oo][1] = 0.f; }
    for (int idx = tid; idx < 16 * 256; idx += 256) {
        int m = idx >> 8, k = idx & 255;
        int crow = crow0 + m;
        int b = crow / TCB_, tl = crow - b * TCB_;
        a_s[idx] = (float)s_r8[((size_t)b * T_ + t0 + tl) * 256 + k];
    }
    __syncthreads();
    for (int k = 0; k < 256; k++) {
        float4 wv = *(const float4*)&fc1T[(size_t)k * 128 + (oq << 2)];
        float w4[4] = {wv.x, wv.y, wv.z, wv.w};
        float a0 = a_s[(mg * 2 + 0) * 256 + k];
        float a1 = a_s[(mg * 2 + 1) * 256 + k];
#pragma unroll
        for (int oo = 0; oo < 4; oo++) {
            acc[oo][0] = fmaf(w4[oo], a0, acc[oo][0]);
            acc[oo][1] = fmaf(w4[oo], a1, acc[oo][1]);
        }
    }
#pragma unroll
    for (int mi = 0; mi < 2; mi++) {
        float* dst = pfc + (size_t)(crow0 + mg * 2 + mi) * 128 + (oq << 2);
#pragma unroll
        for (int oo = 0; oo < 4; oo++)
            dst[oo] = __fadd_rn(acc[oo][mi], fc1_b[(oq << 2) + oo]);
    }
}

// ---------------------------------------------------------------------------
// K10: LIF scan for fc1 layer, back-end chunk, fp32 states st_f.
// ---------------------------------------------------------------------------
__global__ __launch_bounds__(256) void k_scan_f(const float* __restrict__ pfc,
                                                unsigned char* __restrict__ s_f8,
                                                float* __restrict__ st_f,
                                                int t0, int first) {
    int idx = blockIdx.x * 256 + threadIdx.x;   // 8192
    int b = idx >> 7, n = idx & 127;
    float cur, volt, spk;
    if (first) { cur = 0.f; volt = 0.f; spk = 0.f; }
    else { cur = st_f[idx]; volt = st_f[8192 + idx]; spk = st_f[16384 + idx]; }
    for (int tl = 0; tl < TCB_; tl++) {
        lif32(pfc[(size_t)(b * TCB_ + tl) * 128 + n], cur, volt, spk);
        s_f8[((size_t)b * T_ + t0 + tl) * 128 + n] = (unsigned char)spk;
    }
    st_f[idx] = cur; st_f[8192 + idx] = volt; st_f[16384 + idx] = spk;
}

// ---------------------------------------------------------------------------
// K11: out[b,:] = fc2_w @ (sum_t ts[t]*s_f[b,t,:]) — linear head, fp64
// accumulation (differences ~1e-7 are far below the bf16 floor).
// ---------------------------------------------------------------------------
__global__ __launch_bounds__(128) void k_final(const unsigned char* __restrict__ s_f8,
                                               const float* __restrict__ ts,
                                               const float* __restrict__ fc2,
                                               float* __restrict__ out) {
    __shared__ double q_s[128];
    int b = blockIdx.x, k = threadIdx.x;
    double q = 0.0;
    const unsigned char* sf = s_f8 + (size_t)b * T_ * 128 + k;
    for (int t = 0; t < T_; t++) q = fma((double)ts[t], (double)sf[(size_t)t * 128], q);
    q_s[k] = q;
    __syncthreads();
    if (k < 2) {
        double o = 0.0;
        for (int kk = 0; kk < 128; kk++) o = fma((double)fc2[k * 128 + kk], q_s[kk], o);
        out[b * 2 + k] = (float)o;
    }
}

// ---------------------------------------------------------------------------
extern "C" void kernel_launch(void* const* d_in, const int* in_sizes, int n_in,
                              void* d_out, int out_size, void* d_ws, size_t ws_size,
                              hipStream_t stream) {
    const float* x       = (const float*)d_in[0];
    const float* conv1_w = (const float*)d_in[1];
    const float* conv1_b = (const float*)d_in[2];
    const float* conv2_w = (const float*)d_in[3];
    const float* conv2_b = (const float*)d_in[4];
    const float* conv3_w = (const float*)d_in[5];
    const float* conv3_b = (const float*)d_in[6];
    const float* tc_w    = (const float*)d_in[7];
    const float* tc_b    = (const float*)d_in[8];
    const float* rec_w   = (const float*)d_in[9];
    const float* rec_b   = (const float*)d_in[10];
    const float* fc1_w   = (const float*)d_in[11];
    const float* fc1_b   = (const float*)d_in[12];
    const float* fc2_w   = (const float*)d_in[13];
    const float* ts_w    = (const float*)d_in[14];
    float* out = (float*)d_out;
    (void)in_sizes; (void)n_in; (void)out_size;

    // ---- persistent region: 21,299,200 B ----
    char* base = (char*)d_ws;
    float* w2T  = (float*)(base + 0);           //   294,912 B
    float* w3T  = (float*)(base + 294912);      // 1,179,648 B
    float* tcT  = (float*)(base + 1474560);     //   786,432 B
    float* recT = (float*)(base + 2260992);     //   262,144 B (unused)
    float* fc1T = (float*)(base + 2523136);     //   131,072 B
    float* st1  = (float*)(base + 2654208);     // 3,145,728 B
    float* st2  = (float*)(base + 5799936);     // 3,538,944 B
    float* st3  = (float*)(base + 9338880);     //   196,608 B
    float* st_tc= (float*)(base + 9535488);     //   196,608 B
    float* st_f = (float*)(base + 9732096);     //    98,304 B
    unsigned char* s3u8  = (unsigned char*)(base + 9830400);   // 3,276,800 B
    unsigned char* s_tc8 = (unsigned char*)(base + 13107200);  // 3,276,800 B
    unsigned char* s_r8  = (unsigned char*)(base + 16384000);  // 3,276,800 B
    unsigned char* s_f8  = (unsigned char*)(base + 19660800);  // 1,638,400 B

    // ---- chunked scratch region, TCF chosen from ws_size (graph-safe) ----
    const size_t PERS = 21299200;
    const size_t PER_T = 1802240;   // bytes per front-end timestep (B=64)
    int TCF;
    if      (ws_size >= PERS + 40 * PER_T) TCF = 40;
    else if (ws_size >= PERS + 20 * PER_T) TCF = 20;
    else if (ws_size >= PERS +  8 * PER_T) TCF = 8;   // 35.7 MB — proven fit
    else                                   TCF = 4;
    int NCH = T_ / TCF;
    char* cb = base + PERS;
    float* psp2c = (float*)(cb);                                      // TCF*1,179,648 B
    float* psp3c = (float*)(cb + (size_t)TCF * 1179648);              // TCF*65,536 B
    float* pc    = (float*)(cb + (size_t)TCF * (1179648 + 65536));    // TCF*294,912 B
    unsigned char* s1c = (unsigned char*)(cb + (size_t)TCF * (1179648 + 65536 + 294912)); // TCF*262,144 B
    // back-end chunk buffers alias the front-end scratch (dead by then)
    float* ptcc = (float*)(cb);              // 3,276,800 B
    float* pfc  = (float*)(cb + 3276800);    // 1,638,400 B

    k_setup<<<2592, 256, 0, stream>>>(conv2_w, conv3_w, tc_w, rec_w, fc1_w,
                                      w2T, w3T, tcT, recT, fc1T);
    for (int ch = 0; ch < NCH; ch++) {
        int t0 = ch * TCF;
        int first = (ch == 0) ? 1 : 0;
        k_conv1<<<1024, 256, 0, stream>>>(x, conv1_w, conv1_b, s1c, st1, t0, TCF, first);
        k_conv2<<<B_ * TCF / 2, 384, 0, stream>>>(s1c, w2T, conv2_b, psp2c, TCF);
        k_lif2pool<<<288, 256, 0, stream>>>(psp2c, pc, st2, TCF, first);
        k_conv3<<<B_ * TCF / 4, 256, 0, stream>>>(pc, w3T, conv3_b, psp3c);
        k_scan3<<<64, 256, 0, stream>>>(psp3c, s3u8, st3, t0, TCF, first);
    }
    for (int bc = 0; bc < T_ / TCB_; bc++) {
        int t0 = bc * TCB_;
        k_tc<<<B_ * TCB_ / 16, 256, 0, stream>>>(s3u8, tcT, tc_b, ptcc, t0);
        k_scan_tc<<<64, 256, 0, stream>>>(ptcc, s_tc8, st_tc, t0, (bc == 0) ? 1 : 0);
    }
    k_rec<<<64, 512, 0, stream>>>(s_tc8, rec_w, rec_b, s_r8);
    for (int bc = 0; bc < T_ / TCB_; bc++) {
        int t0 = bc * TCB_;
        k_fc1<<<B_ * TCB_ / 16, 256, 0, stream>>>(s_r8, fc1T, fc1_b, pfc, t0);
        k_scan_f<<<32, 256, 0, stream>>>(pfc, s_f8, st_f, t0, (bc == 0) ? 1 : 0);
    }
    k_final<<<64, 128, 0, stream>>>(s_f8, ts_w, fc2_w, out);
}

// Round 13
// 2260.598 us; speedup vs baseline: 1.2828x; 1.2828x over previous
//
#include <hip/hip_runtime.h>

// ---------------------------------------------------------------------------
// CUBA spiking CNN, forward only.
// Numerics contract (match a canonical numpy fp32 trajectory):
//   * every dot/conv = ONE fp32 accumulator per output, sequential fmaf
//     chain in ascending k-order ((c,i,j) for convs, 0..K-1 for matmuls)
//   * bias added AFTER the sum (reference association), unfused
//   * all elementwise/LIF ops unfused fp32 (__fmul_rn/__fadd_rn; no FMA
//     contraction — numpy ufuncs don't contract)
//   * spikes stored u8 (exact), pooled values exact multiples of 0.25
// R19 (base = R16, best 2397us):
//  * k_conv2 retiled: 128 threads/block, ONE (b,t) per block, thread owns
//    ONE oc and computes ALL 36 outputs. Per c: 16 ds_read_b128 serve 324
//    FMA (was 24 reads per oc across 3 threads) -> 1.5x fewer LDS issues,
//    3x FMA:LDS per wave. R18 (u8 unpack) traded LDS for MORE VALU (68%
//    busy, 320us) and is reverted; fp32 staging restored.
//    Per-output chain ascending (c,i,j), identical sequence -> bit-exact.
//  * k_rec = R16 exact (named float4 + waves_per_eu(2,2), 264us).
// ---------------------------------------------------------------------------

#define B_   64
#define T_   200
#define TCB_ 50

__device__ __forceinline__ void lif32(float psp, float& cur, float& volt, float& spk) {
#pragma clang fp contract(off)
    cur  = __fadd_rn(__fmul_rn(0.5f, cur), psp);
    volt = __fadd_rn(__fmul_rn(__fmul_rn(0.75f, volt), __fsub_rn(1.0f, spk)), cur);
    spk  = (volt > 0.5f) ? 1.0f : 0.0f;
}

// ---------------------------------------------------------------------------
// K0: weight transposes (fp32). dst[k*N+o] = src[o*K+k]
// ---------------------------------------------------------------------------
__global__ void k_setup(const float* __restrict__ w2, const float* __restrict__ w3,
                        const float* __restrict__ tcw, const float* __restrict__ recw,
                        const float* __restrict__ fw,
                        float* __restrict__ w2T, float* __restrict__ w3T,
                        float* __restrict__ tcT, float* __restrict__ recT,
                        float* __restrict__ fc1T) {
    int idx = blockIdx.x * 256 + threadIdx.x;
    if (idx < 73728) { int o = idx & 127, k = idx >> 7; w2T[idx] = w2[o * 576 + k]; return; }
    idx -= 73728;
    if (idx < 294912) { int o = idx & 255, k = idx >> 8; w3T[idx] = w3[o * 1152 + k]; return; }
    idx -= 294912;
    if (idx < 196608) { int tap = idx >> 16, r = idx & 65535; int o = r & 255, k = r >> 8;
                        tcT[idx] = tcw[tap * 65536 + o * 256 + k]; return; }
    idx -= 196608;
    if (idx < 65536) { int o = idx & 255, k = idx >> 8; recT[idx] = recw[o * 256 + k]; return; }
    idx -= 65536;
    if (idx < 32768) { int o = idx & 127, k = idx >> 7; fc1T[idx] = fw[o * 256 + k]; return; }
}

// ---------------------------------------------------------------------------
// K1: conv1 (1->64, 3x3, 10x10->8x8) + LIF1, one chunk. Sequential fp32
// fmaf over (i,j); psp = sum + bias (unfused). States fp32 in st1.
// ---------------------------------------------------------------------------
__global__ __launch_bounds__(256) void k_conv1(const float* __restrict__ x,
                                               const float* __restrict__ w1,
                                               const float* __restrict__ b1,
                                               unsigned char* __restrict__ s1c,
                                               float* __restrict__ st1,
                                               int t0, int TC, int first) {
    int idx = blockIdx.x * 256 + threadIdx.x;   // 262144
    int xx = idx & 7, yy = (idx >> 3) & 7, o = (idx >> 6) & 63, b = idx >> 12;
    float w[9];
#pragma unroll
    for (int i = 0; i < 9; i++) w[i] = w1[o * 9 + i];
    float bias = b1[o];
    const float* xb = x + (size_t)b * 20000;
    unsigned char* sb = s1c + (size_t)b * TC * 4096 + (o << 6) + (yy << 3) + xx;
    float cur, volt, spk;
    if (first) { cur = 0.f; volt = 0.f; spk = 0.f; }
    else { cur = st1[idx]; volt = st1[262144 + idx]; spk = st1[524288 + idx]; }
    for (int tl = 0; tl < TC; tl += 4) {
        int t = t0 + tl;
        float a0 = 0.f, a1 = 0.f, a2 = 0.f, a3 = 0.f;
#pragma unroll
        for (int i = 0; i < 3; i++) {
#pragma unroll
            for (int j = 0; j < 3; j++) {
                float4 v = *(const float4*)&xb[((yy + i) * 10 + xx + j) * T_ + t];
                float wv = w[i * 3 + j];
                a0 = fmaf(wv, v.x, a0); a1 = fmaf(wv, v.y, a1);
                a2 = fmaf(wv, v.z, a2); a3 = fmaf(wv, v.w, a3);
            }
        }
        float accs[4] = {a0, a1, a2, a3};
#pragma unroll
        for (int q = 0; q < 4; q++) {
            float psp = __fadd_rn(accs[q], bias);
            lif32(psp, cur, volt, spk);
            sb[(size_t)(tl + q) * 4096] = (unsigned char)spk;
        }
    }
    st1[idx] = cur; st1[262144 + idx] = volt; st1[524288 + idx] = spk;
}

// ---------------------------------------------------------------------------
// K2: conv2 (64->128, 3x3, 8x8->6x6), R19 retile. grid = B*TC blocks,
// 128 threads. Thread = oc: computes ALL 36 outputs (6y x 6x) for one
// (b,t). Per c: 9 coalesced weight dwords + 16 wave-uniform ds_read_b128
// (8 rows) serving 324 FMA. Stores coalesced (psp2c[b][t][y][x][oc]).
// Per output (y,x): sequential fmaf over (c,i,j) ascending; +bias after.
// ---------------------------------------------------------------------------
__global__ __launch_bounds__(128) void k_conv2(const unsigned char* __restrict__ s1c,
                                               const float* __restrict__ w2T,
                                               const float* __restrict__ b2,
                                               float* __restrict__ psp2c, int TC) {
    __shared__ float s_s[4096];                 // [c=64][y=8][x=8]
    int blk = blockIdx.x;                       // b*TC + tl
    int tid = threadIdx.x;                      // = oc
    const unsigned int* src4 = (const unsigned int*)(s1c + (size_t)blk * 4096);
    for (int i = tid; i < 1024; i += 128) {
        unsigned int u = src4[i];
        s_s[4 * i + 0] = (float)(u & 0xff);
        s_s[4 * i + 1] = (float)((u >> 8) & 0xff);
        s_s[4 * i + 2] = (float)((u >> 16) & 0xff);
        s_s[4 * i + 3] = (float)(u >> 24);
    }
    __syncthreads();
    int oc = tid;
    float acc[6][6];
#pragma unroll
    for (int y = 0; y < 6; y++)
#pragma unroll
        for (int x = 0; x < 6; x++) acc[y][x] = 0.f;
    const float* wb = w2T + oc;
    for (int c = 0; c < 64; c++) {
        // 9 weights, lane-consecutive in oc -> coalesced
        float w[9];
#pragma unroll
        for (int q = 0; q < 9; q++) w[q] = wb[(size_t)(c * 9 + q) * 128];
        // 8 input rows, wave-uniform broadcast reads (conflict-free)
        const float* sc = &s_s[c * 64];
        float row[8][8];
#pragma unroll
        for (int ry = 0; ry < 8; ry++) {
            float4 fa = *(const float4*)(sc + ry * 8);
            float4 fb = *(const float4*)(sc + ry * 8 + 4);
            row[ry][0] = fa.x; row[ry][1] = fa.y; row[ry][2] = fa.z; row[ry][3] = fa.w;
            row[ry][4] = fb.x; row[ry][5] = fb.y; row[ry][6] = fb.z; row[ry][7] = fb.w;
        }
#pragma unroll
        for (int i = 0; i < 3; i++)
#pragma unroll
            for (int j = 0; j < 3; j++) {
                float wv = w[i * 3 + j];
#pragma unroll
                for (int y = 0; y < 6; y++)
#pragma unroll
                    for (int x = 0; x < 6; x++)
                        acc[y][x] = fmaf(wv, row[y + i][x + j], acc[y][x]);
            }
    }
    float bv = b2[oc];
    float* base = psp2c + (size_t)blk * 4608 + oc;
#pragma unroll
    for (int y = 0; y < 6; y++)
#pragma unroll
        for (int x = 0; x < 6; x++)
            base[(size_t)(y * 6 + x) * 128] = __fadd_rn(acc[y][x], bv);
}

// ---------------------------------------------------------------------------
// K3: LIF2 + AvgPool(2), fp32 states (12 planes x 73728 in st2), chunk.
// psp2c layout [b][t][y][x][oc]; thread = (b, pos, oc), oc in low bits ->
// the 4 quad reads are lane-consecutive (coalesced). Quad order unchanged.
// pc: fp32 [b*TC+tl][oc*9+pos] (unchanged layout for conv3).
// ---------------------------------------------------------------------------
__global__ __launch_bounds__(256) void k_lif2pool(const float* __restrict__ psp2c,
                                                  float* __restrict__ pc,
                                                  float* __restrict__ st2,
                                                  int TC, int first) {
    int idx = blockIdx.x * 256 + threadIdx.x;   // 73728
    int oc = idx & 127;
    int r = idx >> 7;                           // b*9 + pos
    int pos = r % 9;
    int b = r / 9;
    int py = pos / 3, px = pos - py * 3;
    const float* pb = psp2c + (size_t)b * TC * 4608;
    int off00 = ((2 * py) * 6 + 2 * px) * 128 + oc;
    int off01 = ((2 * py) * 6 + 2 * px + 1) * 128 + oc;
    int off10 = ((2 * py + 1) * 6 + 2 * px) * 128 + oc;
    int off11 = ((2 * py + 1) * 6 + 2 * px + 1) * 128 + oc;
    float* pd = pc + (size_t)b * TC * 1152 + oc * 9 + pos;
    float c0, c1, c2, c3, v0, v1, v2, v3, s0, s1, s2, s3;
    if (first) {
        c0 = c1 = c2 = c3 = v0 = v1 = v2 = v3 = s0 = s1 = s2 = s3 = 0.f;
    } else {
        c0 = st2[idx];              c1 = st2[73728 + idx];
        c2 = st2[147456 + idx];     c3 = st2[221184 + idx];
        v0 = st2[294912 + idx];     v1 = st2[368640 + idx];
        v2 = st2[442368 + idx];     v3 = st2[516096 + idx];
        s0 = st2[589824 + idx];     s1 = st2[663552 + idx];
        s2 = st2[737280 + idx];     s3 = st2[811008 + idx];
    }
    for (int tl = 0; tl < TC; tl++) {
        const float* pt = pb + (size_t)tl * 4608;
        float p0 = pt[off00];
        float p1 = pt[off01];
        float p2 = pt[off10];
        float p3 = pt[off11];
        lif32(p0, c0, v0, s0);
        lif32(p1, c1, v1, s1);
        lif32(p2, c2, v2, s2);
        lif32(p3, c3, v3, s3);
        // sum of 0/1 values: exact in any order; *0.25 exact
        pd[(size_t)tl * 1152] = __fmul_rn(0.25f, __fadd_rn(__fadd_rn(__fadd_rn(s0, s1), s2), s3));
    }
    st2[idx] = c0;           st2[73728 + idx] = c1;
    st2[147456 + idx] = c2;  st2[221184 + idx] = c3;
    st2[294912 + idx] = v0;  st2[368640 + idx] = v1;
    st2[442368 + idx] = v2;  st2[516096 + idx] = v3;
    st2[589824 + idx] = s0;  st2[663552 + idx] = s1;
    st2[737280 + idx] = s2;  st2[811008 + idx] = s3;
}

// ---------------------------------------------------------------------------
// K4: conv3 GEMM, 4 rows x 256 outputs per block. Per output: sequential
// fp32 fmaf k=0..1151 ascending. Epilogue: +bias unfused.
// ---------------------------------------------------------------------------
__global__ __launch_bounds__(256) void k_conv3(const float* __restrict__ pc,
                                               const float* __restrict__ w3T,
                                               const float* __restrict__ b3,
                                               float* __restrict__ psp3c) {
    __shared__ float a_s[4 * 1152];
    int row0 = blockIdx.x * 4;
    int tid = threadIdx.x;
    int oq = tid & 63, mg = tid >> 6;           // 64 output-quads x 4 rows
    for (int idx = tid; idx < 4 * 1152; idx += 256) {
        int m = idx / 1152, k = idx - m * 1152;
        a_s[idx] = pc[(size_t)(row0 + m) * 1152 + k];
    }
    __syncthreads();
    float acc[4] = {0.f, 0.f, 0.f, 0.f};
    const float* as_row = &a_s[mg * 1152];      // wave-uniform -> broadcast reads
#pragma unroll 4
    for (int k = 0; k < 1152; k++) {
        float4 wv = *(const float4*)&w3T[(size_t)k * 256 + (oq << 2)];
        float am = as_row[k];
        acc[0] = fmaf(wv.x, am, acc[0]);
        acc[1] = fmaf(wv.y, am, acc[1]);
        acc[2] = fmaf(wv.z, am, acc[2]);
        acc[3] = fmaf(wv.w, am, acc[3]);
    }
    float* dst = psp3c + (size_t)(row0 + mg) * 256 + (oq << 2);
#pragma unroll
    for (int oo = 0; oo < 4; oo++)
        dst[oo] = __fadd_rn(acc[oo], b3[(oq << 2) + oo]);
}

// ---------------------------------------------------------------------------
// K5: LIF3 scan on chunk, fp32 states (st3), writes u8 s3u8[b][t][256].
// ---------------------------------------------------------------------------
__global__ __launch_bounds__(256) void k_scan3(const float* __restrict__ psp3c,
                                               unsigned char* __restrict__ s3u8,
                                               float* __restrict__ st3,
                                               int t0, int TC, int first) {
    int idx = blockIdx.x * 256 + threadIdx.x;   // 16384
    int b = idx >> 8, n = idx & 255;
    float cur, volt, spk;
    if (first) { cur = 0.f; volt = 0.f; spk = 0.f; }
    else { cur = st3[idx]; volt = st3[16384 + idx]; spk = st3[32768 + idx]; }
    for (int tl = 0; tl < TC; tl++) {
        lif32(psp3c[(size_t)(b * TC + tl) * 256 + n], cur, volt, spk);
        s3u8[((size_t)b * T_ + t0 + tl) * 256 + n] = (unsigned char)spk;
    }
    st3[idx] = cur; st3[16384 + idx] = volt; st3[32768 + idx] = spk;
}

// ---------------------------------------------------------------------------
// K6: temporal conv, back-end chunk TCB=50. Per tap: sequential fp32 dot
// (k=0..255) -> +bias (unfused) -> gated sequential psum (numpy order).
// ---------------------------------------------------------------------------
__global__ __launch_bounds__(256) void k_tc(const unsigned char* __restrict__ s3u8,
                                            const float* __restrict__ tcT,
                                            const float* __restrict__ tc_b,
                                            float* __restrict__ ptcc, int t0) {
    __shared__ float a_s[16 * 256];
    int crow0 = blockIdx.x * 16;
    int tid = threadIdx.x;
    int oq = tid & 63, mg = tid >> 6;
    float psum[4][4];
#pragma unroll
    for (int oo = 0; oo < 4; oo++)
#pragma unroll
        for (int mi = 0; mi < 4; mi++) psum[oo][mi] = 0.f;
    for (int tap = 0; tap < 3; tap++) {
        __syncthreads();
        for (int idx = tid; idx < 16 * 256; idx += 256) {
            int m = idx >> 8, k = idx & 255;
            int crow = crow0 + m;
            int b = crow / TCB_, tl = crow - b * TCB_;
            int t = t0 + tl;
            float v = 0.f;
            if (t >= tap) v = (float)s3u8[((size_t)b * T_ + t - tap) * 256 + k];
            a_s[idx] = v;
        }
        __syncthreads();
        float acc[4][4];
#pragma unroll
        for (int oo = 0; oo < 4; oo++)
#pragma unroll
            for (int mi = 0; mi < 4; mi++) acc[oo][mi] = 0.f;
        const float* wbase = tcT + (size_t)tap * 65536 + (oq << 2);
        for (int k = 0; k < 256; k++) {
            float4 wv = *(const float4*)(wbase + (size_t)k * 256);
            float w4[4] = {wv.x, wv.y, wv.z, wv.w};
            float am[4];
#pragma unroll
            for (int mi = 0; mi < 4; mi++) am[mi] = a_s[(mg * 4 + mi) * 256 + k];
#pragma unroll
            for (int oo = 0; oo < 4; oo++)
#pragma unroll
                for (int mi = 0; mi < 4; mi++)
                    acc[oo][mi] = fmaf(w4[oo], am[mi], acc[oo][mi]);
        }
#pragma unroll
        for (int mi = 0; mi < 4; mi++) {
            int crow = crow0 + mg * 4 + mi;
            int b = crow / TCB_, tl = crow - b * TCB_;
            int t = t0 + tl;
            float g = (t >= tap) ? 1.0f : 0.0f;
#pragma unroll
            for (int oo = 0; oo < 4; oo++) {
                int oc = (oq << 2) + oo;
                float tap_f = __fadd_rn(acc[oo][mi], tc_b[tap * 256 + oc]);
                psum[oo][mi] = __fadd_rn(psum[oo][mi], __fmul_rn(g, tap_f));
            }
        }
    }
#pragma unroll
    for (int mi = 0; mi < 4; mi++) {
        int crow = crow0 + mg * 4 + mi;
        float* dst = ptcc + (size_t)crow * 256 + (oq << 2);
#pragma unroll
        for (int oo = 0; oo < 4; oo++) dst[oo] = psum[oo][mi];
    }
}

// ---------------------------------------------------------------------------
// K7: LIF scan for tc layer, back-end chunk, fp32 states st_tc.
// ---------------------------------------------------------------------------
__global__ __launch_bounds__(256) void k_scan_tc(const float* __restrict__ ptcc,
                                                 unsigned char* __restrict__ s_tc8,
                                                 float* __restrict__ st_tc,
                                                 int t0, int first) {
    int idx = blockIdx.x * 256 + threadIdx.x;   // 16384
    int b = idx >> 8, n = idx & 255;
    float cur, volt, spk;
    if (first) { cur = 0.f; volt = 0.f; spk = 0.f; }
    else { cur = st_tc[idx]; volt = st_tc[16384 + idx]; spk = st_tc[32768 + idx]; }
    for (int tl = 0; tl < TCB_; tl++) {
        lif32(ptcc[(size_t)(b * TCB_ + tl) * 256 + n], cur, volt, spk);
        s_tc8[((size_t)b * T_ + t0 + tl) * 256 + n] = (unsigned char)spk;
    }
    st_tc[idx] = cur; st_tc[16384 + idx] = volt; st_tc[32768 + idx] = spk;
}

// ---------------------------------------------------------------------------
// K8: recurrent layer, split-chain, NAMED-float4 register weights +
// amdgpu_waves_per_eu(2,2) (R16 exact — measured 264us best).
// 512 threads/block, WG per batch element. Thread (o = tid&255,
// half = tid>>8) holds its 128-weight slice in 32 NAMED float4 variables.
// Per step:
//   half 0: acc = chain(0, k=0..127)          -> acc_s[o]
//   barrier
//   half 1: acc = chain(acc_s[o], k=128..255) -> +stc +rb -> LIF -> store,
//           publish spike to spk_s[p^1]
//   barrier
// chain(chain(0,k<128),k>=128) is the IDENTICAL fmaf sequence as the single
// 256-link chain -> bit-identical. fmaf(s,w,acc) with s in {0,1} is
// bit-identical to __fadd_rn(acc, s?w:0). Branches wave-uniform.
// ---------------------------------------------------------------------------
__global__ __launch_bounds__(512)
__attribute__((amdgpu_waves_per_eu(2, 2)))
void k_rec(const unsigned char* __restrict__ s_tc8,
           const float* __restrict__ rec_w,
           const float* __restrict__ rec_b,
           unsigned char* __restrict__ s_r8) {
    __shared__ __align__(16) float spk_s[2][256];
    __shared__ float acc_s[256];
    int b = blockIdx.x;
    int tid = threadIdx.x;
    int o = tid & 255, half = tid >> 8;
    const float* wrow = rec_w + (size_t)o * 256 + (half << 7);
#define WD(i) float4 w##i = *(const float4*)&wrow[4 * i];
    WD(0)  WD(1)  WD(2)  WD(3)  WD(4)  WD(5)  WD(6)  WD(7)
    WD(8)  WD(9)  WD(10) WD(11) WD(12) WD(13) WD(14) WD(15)
    WD(16) WD(17) WD(18) WD(19) WD(20) WD(21) WD(22) WD(23)
    WD(24) WD(25) WD(26) WD(27) WD(28) WD(29) WD(30) WD(31)
#undef WD
    if (half == 0) spk_s[0][o] = 0.f;
    float cur = 0.f, volt = 0.f, spk = 0.f;
    float rb = rec_b[o];
    const unsigned char* stp = s_tc8 + (size_t)b * T_ * 256 + o;
    unsigned char* srp = s_r8 + (size_t)b * T_ * 256 + o;
    __syncthreads();
    int p = 0;
    // CH(i): 4 chain links using float4 i (ascending k within the slice)
#define CH(i, sp) { float4 sv = *(const float4*)&(sp)[4 * i]; \
        acc = fmaf(sv.x, w##i.x, acc); acc = fmaf(sv.y, w##i.y, acc); \
        acc = fmaf(sv.z, w##i.z, acc); acc = fmaf(sv.w, w##i.w, acc); }
#define CHAIN32(sp) \
    CH(0,sp)  CH(1,sp)  CH(2,sp)  CH(3,sp)  CH(4,sp)  CH(5,sp)  CH(6,sp)  CH(7,sp) \
    CH(8,sp)  CH(9,sp)  CH(10,sp) CH(11,sp) CH(12,sp) CH(13,sp) CH(14,sp) CH(15,sp) \
    CH(16,sp) CH(17,sp) CH(18,sp) CH(19,sp) CH(20,sp) CH(21,sp) CH(22,sp) CH(23,sp) \
    CH(24,sp) CH(25,sp) CH(26,sp) CH(27,sp) CH(28,sp) CH(29,sp) CH(30,sp) CH(31,sp)
    for (int t = 0; t < T_; t++) {
        if (half == 0) {
            const float* sp = spk_s[p];
            float acc = 0.f;
            CHAIN32(sp)
            acc_s[o] = acc;
        }
        __syncthreads();                // publish partial acc
        if (half == 1) {
            float stc = (float)stp[(size_t)t * 256];   // independent, issues early
            const float* sp = spk_s[p] + 128;
            float acc = acc_s[o];
            CHAIN32(sp)
            float psp = __fadd_rn(__fadd_rn(stc, acc), rb);
            lif32(psp, cur, volt, spk);
            srp[(size_t)t * 256] = (unsigned char)spk;
            spk_s[p ^ 1][o] = spk;      // publish spike for next step
        }
        __syncthreads();
        p ^= 1;
    }
#undef CH
#undef CHAIN32
}

// ---------------------------------------------------------------------------
// K9: fc1 GEMM, back-end chunk. Sequential fp32 fmaf k=0..255; +bias after.
// ---------------------------------------------------------------------------
__global__ __launch_bounds__(256) void k_fc1(const unsigned char* __restrict__ s_r8,
                                             const float* __restrict__ fc1T,
                                             const float* __restrict__ fc1_b,
                                             float* __restrict__ pfc, int t0) {
    __shared__ float a_s[16 * 256];
    int crow0 = blockIdx.x * 16;
    int tid = threadIdx.x;
    int oq = tid & 31, mg = tid >> 5;           // 8 m-groups, tile 2m
    float acc[4][2];
#pragma unroll
    for (int oo = 0; oo < 4; oo++) { acc[oo][0] = 0.f; acc[oo][1] = 0.f; }
    for (int idx = tid; idx < 16 * 256; idx += 256) {
        int m = idx >> 8, k = idx & 255;
        int crow = crow0 + m;
        int b = crow / TCB_, tl = crow - b * TCB_;
        a_s[idx] = (float)s_r8[((size_t)b * T_ + t0 + tl) * 256 + k];
    }
    __syncthreads();
    for (int k = 0; k < 256; k++) {
        float4 wv = *(const float4*)&fc1T[(size_t)k * 128 + (oq << 2)];
        float w4[4] = {wv.x, wv.y, wv.z, wv.w};
        float a0 = a_s[(mg * 2 + 0) * 256 + k];
        float a1 = a_s[(mg * 2 + 1) * 256 + k];
#pragma unroll
        for (int oo = 0; oo < 4; oo++) {
            acc[oo][0] = fmaf(w4[oo], a0, acc[oo][0]);
            acc[oo][1] = fmaf(w4[oo], a1, acc[oo][1]);
        }
    }
#pragma unroll
    for (int mi = 0; mi < 2; mi++) {
        float* dst = pfc + (size_t)(crow0 + mg * 2 + mi) * 128 + (oq << 2);
#pragma unroll
        for (int oo = 0; oo < 4; oo++)
            dst[oo] = __fadd_rn(acc[oo][mi], fc1_b[(oq << 2) + oo]);
    }
}

// ---------------------------------------------------------------------------
// K10: LIF scan for fc1 layer, back-end chunk, fp32 states st_f.
// ---------------------------------------------------------------------------
__global__ __launch_bounds__(256) void k_scan_f(const float* __restrict__ pfc,
                                                unsigned char* __restrict__ s_f8,
                                                float* __restrict__ st_f,
                                                int t0, int first) {
    int idx = blockIdx.x * 256 + threadIdx.x;   // 8192
    int b = idx >> 7, n = idx & 127;
    float cur, volt, spk;
    if (first) { cur = 0.f; volt = 0.f; spk = 0.f; }
    else { cur = st_f[idx]; volt = st_f[8192 + idx]; spk = st_f[16384 + idx]; }
    for (int tl = 0; tl < TCB_; tl++) {
        lif32(pfc[(size_t)(b * TCB_ + tl) * 128 + n], cur, volt, spk);
        s_f8[((size_t)b * T_ + t0 + tl) * 128 + n] = (unsigned char)spk;
    }
    st_f[idx] = cur; st_f[8192 + idx] = volt; st_f[16384 + idx] = spk;
}

// ---------------------------------------------------------------------------
// K11: out[b,:] = fc2_w @ (sum_t ts[t]*s_f[b,t,:]) — linear head, fp64
// accumulation (differences ~1e-7 are far below the bf16 floor).
// ---------------------------------------------------------------------------
__global__ __launch_bounds__(128) void k_final(const unsigned char* __restrict__ s_f8,
                                               const float* __restrict__ ts,
                                               const float* __restrict__ fc2,
                                               float* __restrict__ out) {
    __shared__ double q_s[128];
    int b = blockIdx.x, k = threadIdx.x;
    double q = 0.0;
    const unsigned char* sf = s_f8 + (size_t)b * T_ * 128 + k;
    for (int t = 0; t < T_; t++) q = fma((double)ts[t], (double)sf[(size_t)t * 128], q);
    q_s[k] = q;
    __syncthreads();
    if (k < 2) {
        double o = 0.0;
        for (int kk = 0; kk < 128; kk++) o = fma((double)fc2[k * 128 + kk], q_s[kk], o);
        out[b * 2 + k] = (float)o;
    }
}

// ---------------------------------------------------------------------------
extern "C" void kernel_launch(void* const* d_in, const int* in_sizes, int n_in,
                              void* d_out, int out_size, void* d_ws, size_t ws_size,
                              hipStream_t stream) {
    const float* x       = (const float*)d_in[0];
    const float* conv1_w = (const float*)d_in[1];
    const float* conv1_b = (const float*)d_in[2];
    const float* conv2_w = (const float*)d_in[3];
    const float* conv2_b = (const float*)d_in[4];
    const float* conv3_w = (const float*)d_in[5];
    const float* conv3_b = (const float*)d_in[6];
    const float* tc_w    = (const float*)d_in[7];
    const float* tc_b    = (const float*)d_in[8];
    const float* rec_w   = (const float*)d_in[9];
    const float* rec_b   = (const float*)d_in[10];
    const float* fc1_w   = (const float*)d_in[11];
    const float* fc1_b   = (const float*)d_in[12];
    const float* fc2_w   = (const float*)d_in[13];
    const float* ts_w    = (const float*)d_in[14];
    float* out = (float*)d_out;
    (void)in_sizes; (void)n_in; (void)out_size;

    // ---- persistent region: 21,299,200 B ----
    char* base = (char*)d_ws;
    float* w2T  = (float*)(base + 0);           //   294,912 B
    float* w3T  = (float*)(base + 294912);      // 1,179,648 B
    float* tcT  = (float*)(base + 1474560);     //   786,432 B
    float* recT = (float*)(base + 2260992);     //   262,144 B (unused)
    float* fc1T = (float*)(base + 2523136);     //   131,072 B
    float* st1  = (float*)(base + 2654208);     // 3,145,728 B
    float* st2  = (float*)(base + 5799936);     // 3,538,944 B
    float* st3  = (float*)(base + 9338880);     //   196,608 B
    float* st_tc= (float*)(base + 9535488);     //   196,608 B
    float* st_f = (float*)(base + 9732096);     //    98,304 B
    unsigned char* s3u8  = (unsigned char*)(base + 9830400);   // 3,276,800 B
    unsigned char* s_tc8 = (unsigned char*)(base + 13107200);  // 3,276,800 B
    unsigned char* s_r8  = (unsigned char*)(base + 16384000);  // 3,276,800 B
    unsigned char* s_f8  = (unsigned char*)(base + 19660800);  // 1,638,400 B

    // ---- chunked scratch region, TCF chosen from ws_size (graph-safe) ----
    const size_t PERS = 21299200;
    const size_t PER_T = 1802240;   // bytes per front-end timestep (B=64)
    int TCF;
    if      (ws_size >= PERS + 40 * PER_T) TCF = 40;
    else if (ws_size >= PERS + 20 * PER_T) TCF = 20;
    else if (ws_size >= PERS +  8 * PER_T) TCF = 8;   // 35.7 MB — proven fit
    else                                   TCF = 4;
    int NCH = T_ / TCF;
    char* cb = base + PERS;
    float* psp2c = (float*)(cb);                                      // TCF*1,179,648 B
    float* psp3c = (float*)(cb + (size_t)TCF * 1179648);              // TCF*65,536 B
    float* pc    = (float*)(cb + (size_t)TCF * (1179648 + 65536));    // TCF*294,912 B
    unsigned char* s1c = (unsigned char*)(cb + (size_t)TCF * (1179648 + 65536 + 294912)); // TCF*262,144 B
    // back-end chunk buffers alias the front-end scratch (dead by then)
    float* ptcc = (float*)(cb);              // 3,276,800 B
    float* pfc  = (float*)(cb + 3276800);    // 1,638,400 B

    k_setup<<<2592, 256, 0, stream>>>(conv2_w, conv3_w, tc_w, rec_w, fc1_w,
                                      w2T, w3T, tcT, recT, fc1T);
    for (int ch = 0; ch < NCH; ch++) {
        int t0 = ch * TCF;
        int first = (ch == 0) ? 1 : 0;
        k_conv1<<<1024, 256, 0, stream>>>(x, conv1_w, conv1_b, s1c, st1, t0, TCF, first);
        k_conv2<<<B_ * TCF, 128, 0, stream>>>(s1c, w2T, conv2_b, psp2c, TCF);
        k_lif2pool<<<288, 256, 0, stream>>>(psp2c, pc, st2, TCF, first);
        k_conv3<<<B_ * TCF / 4, 256, 0, stream>>>(pc, w3T, conv3_b, psp3c);
        k_scan3<<<64, 256, 0, stream>>>(psp3c, s3u8, st3, t0, TCF, first);
    }
    for (int bc = 0; bc < T_ / TCB_; bc++) {
        int t0 = bc * TCB_;
        k_tc<<<B_ * TCB_ / 16, 256, 0, stream>>>(s3u8, tcT, tc_b, ptcc, t0);
        k_scan_tc<<<64, 256, 0, stream>>>(ptcc, s_tc8, st_tc, t0, (bc == 0) ? 1 : 0);
    }
    k_rec<<<64, 512, 0, stream>>>(s_tc8, rec_w, rec_b, s_r8);
    for (int bc = 0; bc < T_ / TCB_; bc++) {
        int t0 = bc * TCB_;
        k_fc1<<<B_ * TCB_ / 16, 256, 0, stream>>>(s_r8, fc1T, fc1_b, pfc, t0);
        k_scan_f<<<32, 256, 0, stream>>>(pfc, s_f8, st_f, t0, (bc == 0) ? 1 : 0);
    }
    k_final<<<64, 128, 0, stream>>>(s_f8, ts_w, fc2_w, out);
}

// Round 14
// 2170.655 us; speedup vs baseline: 1.3360x; 1.0414x over previous
//
#include <hip/hip_runtime.h>

// ---------------------------------------------------------------------------
// CUBA spiking CNN, forward only.
// Numerics contract (match a canonical numpy fp32 trajectory):
//   * every dot/conv = ONE fp32 accumulator per output, sequential fmaf
//     chain in ascending k-order ((c,i,j) for convs, 0..K-1 for matmuls)
//   * bias added AFTER the sum (reference association), unfused
//   * all elementwise/LIF ops unfused fp32 (__fmul_rn/__fadd_rn; no FMA
//     contraction — numpy ufuncs don't contract)
//   * spikes stored u8 (exact), pooled values exact multiples of 0.25
// R20 (base = R19, best 2260us): ONE change — k_conv1 stages its input
// tile in LDS. The old inner loop issued 9 float4 loads/4t at per-lane
// stride 800B (lanes vary (yy,xx); only t contiguous) -> each wave load
// fragments into ~64 16B L1/L2 requests (~377MB of request traffic per
// dispatch vs 5MB unique). Now: block (one b) copies x[b][pix][t0..t0+TC)
// = 100 x TC floats coalesced into xs[100][44] (stride 44: 176B = 16B-
// aligned float4 rows, 44%32=12 spreads LDS bank starts), then the inner
// loop reads the IDENTICAL values in the IDENTICAL order from LDS ->
// bit-exact. conv2 = R19 retile; k_rec = R16 (264us).
// ---------------------------------------------------------------------------

#define B_   64
#define T_   200
#define TCB_ 50

__device__ __forceinline__ void lif32(float psp, float& cur, float& volt, float& spk) {
#pragma clang fp contract(off)
    cur  = __fadd_rn(__fmul_rn(0.5f, cur), psp);
    volt = __fadd_rn(__fmul_rn(__fmul_rn(0.75f, volt), __fsub_rn(1.0f, spk)), cur);
    spk  = (volt > 0.5f) ? 1.0f : 0.0f;
}

// ---------------------------------------------------------------------------
// K0: weight transposes (fp32). dst[k*N+o] = src[o*K+k]
// ---------------------------------------------------------------------------
__global__ void k_setup(const float* __restrict__ w2, const float* __restrict__ w3,
                        const float* __restrict__ tcw, const float* __restrict__ recw,
                        const float* __restrict__ fw,
                        float* __restrict__ w2T, float* __restrict__ w3T,
                        float* __restrict__ tcT, float* __restrict__ recT,
                        float* __restrict__ fc1T) {
    int idx = blockIdx.x * 256 + threadIdx.x;
    if (idx < 73728) { int o = idx & 127, k = idx >> 7; w2T[idx] = w2[o * 576 + k]; return; }
    idx -= 73728;
    if (idx < 294912) { int o = idx & 255, k = idx >> 8; w3T[idx] = w3[o * 1152 + k]; return; }
    idx -= 294912;
    if (idx < 196608) { int tap = idx >> 16, r = idx & 65535; int o = r & 255, k = r >> 8;
                        tcT[idx] = tcw[tap * 65536 + o * 256 + k]; return; }
    idx -= 196608;
    if (idx < 65536) { int o = idx & 255, k = idx >> 8; recT[idx] = recw[o * 256 + k]; return; }
    idx -= 65536;
    if (idx < 32768) { int o = idx & 127, k = idx >> 7; fc1T[idx] = fw[o * 256 + k]; return; }
}

// ---------------------------------------------------------------------------
// K1: conv1 (1->64, 3x3, 10x10->8x8) + LIF1, one chunk, LDS-staged input
// (R20). Block = one b (16 blocks/b share it): stage x[b][pix][t0..t0+TC)
// into xs[pix][44-padded] with coalesced global reads; inner loop reads
// the same values in the same order from LDS. Sequential fp32 fmaf over
// (i,j); psp = sum + bias (unfused). States fp32 in st1. Bit-exact.
// ---------------------------------------------------------------------------
__global__ __launch_bounds__(256) void k_conv1(const float* __restrict__ x,
                                               const float* __restrict__ w1,
                                               const float* __restrict__ b1,
                                               unsigned char* __restrict__ s1c,
                                               float* __restrict__ st1,
                                               int t0, int TC, int first) {
    __shared__ float xs[100][44];               // TC <= 40; stride 44 (aligned+spread)
    int idx = blockIdx.x * 256 + threadIdx.x;   // 262144
    int tid = threadIdx.x;
    int xx = idx & 7, yy = (idx >> 3) & 7, o = (idx >> 6) & 63, b = idx >> 12;
    const float* xb = x + (size_t)b * 20000;
    // stage: 100 pixel-rows x TC floats, coalesced over t
    for (int i = tid; i < 100 * TC; i += 256) {
        int pix = i / TC, tt = i - pix * TC;
        xs[pix][tt] = xb[pix * 200 + t0 + tt];
    }
    float w[9];
#pragma unroll
    for (int i = 0; i < 9; i++) w[i] = w1[o * 9 + i];
    float bias = b1[o];
    unsigned char* sb = s1c + (size_t)b * TC * 4096 + (o << 6) + (yy << 3) + xx;
    float cur, volt, spk;
    if (first) { cur = 0.f; volt = 0.f; spk = 0.f; }
    else { cur = st1[idx]; volt = st1[262144 + idx]; spk = st1[524288 + idx]; }
    __syncthreads();
    for (int tl = 0; tl < TC; tl += 4) {
        float a0 = 0.f, a1 = 0.f, a2 = 0.f, a3 = 0.f;
#pragma unroll
        for (int i = 0; i < 3; i++) {
#pragma unroll
            for (int j = 0; j < 3; j++) {
                float4 v = *(const float4*)&xs[(yy + i) * 10 + xx + j][tl];
                float wv = w[i * 3 + j];
                a0 = fmaf(wv, v.x, a0); a1 = fmaf(wv, v.y, a1);
                a2 = fmaf(wv, v.z, a2); a3 = fmaf(wv, v.w, a3);
            }
        }
        float accs[4] = {a0, a1, a2, a3};
#pragma unroll
        for (int q = 0; q < 4; q++) {
            float psp = __fadd_rn(accs[q], bias);
            lif32(psp, cur, volt, spk);
            sb[(size_t)(tl + q) * 4096] = (unsigned char)spk;
        }
    }
    st1[idx] = cur; st1[262144 + idx] = volt; st1[524288 + idx] = spk;
}

// ---------------------------------------------------------------------------
// K2: conv2 (64->128, 3x3, 8x8->6x6), R19 retile. grid = B*TC blocks,
// 128 threads. Thread = oc: computes ALL 36 outputs (6y x 6x) for one
// (b,t). Per c: 9 coalesced weight dwords + 16 wave-uniform ds_read_b128
// (8 rows) serving 324 FMA. Stores coalesced (psp2c[b][t][y][x][oc]).
// Per output (y,x): sequential fmaf over (c,i,j) ascending; +bias after.
// ---------------------------------------------------------------------------
__global__ __launch_bounds__(128) void k_conv2(const unsigned char* __restrict__ s1c,
                                               const float* __restrict__ w2T,
                                               const float* __restrict__ b2,
                                               float* __restrict__ psp2c, int TC) {
    __shared__ float s_s[4096];                 // [c=64][y=8][x=8]
    int blk = blockIdx.x;                       // b*TC + tl
    int tid = threadIdx.x;                      // = oc
    const unsigned int* src4 = (const unsigned int*)(s1c + (size_t)blk * 4096);
    for (int i = tid; i < 1024; i += 128) {
        unsigned int u = src4[i];
        s_s[4 * i + 0] = (float)(u & 0xff);
        s_s[4 * i + 1] = (float)((u >> 8) & 0xff);
        s_s[4 * i + 2] = (float)((u >> 16) & 0xff);
        s_s[4 * i + 3] = (float)(u >> 24);
    }
    __syncthreads();
    int oc = tid;
    float acc[6][6];
#pragma unroll
    for (int y = 0; y < 6; y++)
#pragma unroll
        for (int x = 0; x < 6; x++) acc[y][x] = 0.f;
    const float* wb = w2T + oc;
    for (int c = 0; c < 64; c++) {
        // 9 weights, lane-consecutive in oc -> coalesced
        float w[9];
#pragma unroll
        for (int q = 0; q < 9; q++) w[q] = wb[(size_t)(c * 9 + q) * 128];
        // 8 input rows, wave-uniform broadcast reads (conflict-free)
        const float* sc = &s_s[c * 64];
        float row[8][8];
#pragma unroll
        for (int ry = 0; ry < 8; ry++) {
            float4 fa = *(const float4*)(sc + ry * 8);
            float4 fb = *(const float4*)(sc + ry * 8 + 4);
            row[ry][0] = fa.x; row[ry][1] = fa.y; row[ry][2] = fa.z; row[ry][3] = fa.w;
            row[ry][4] = fb.x; row[ry][5] = fb.y; row[ry][6] = fb.z; row[ry][7] = fb.w;
        }
#pragma unroll
        for (int i = 0; i < 3; i++)
#pragma unroll
            for (int j = 0; j < 3; j++) {
                float wv = w[i * 3 + j];
#pragma unroll
                for (int y = 0; y < 6; y++)
#pragma unroll
                    for (int x = 0; x < 6; x++)
                        acc[y][x] = fmaf(wv, row[y + i][x + j], acc[y][x]);
            }
    }
    float bv = b2[oc];
    float* base = psp2c + (size_t)blk * 4608 + oc;
#pragma unroll
    for (int y = 0; y < 6; y++)
#pragma unroll
        for (int x = 0; x < 6; x++)
            base[(size_t)(y * 6 + x) * 128] = __fadd_rn(acc[y][x], bv);
}

// ---------------------------------------------------------------------------
// K3: LIF2 + AvgPool(2), fp32 states (12 planes x 73728 in st2), chunk.
// psp2c layout [b][t][y][x][oc]; thread = (b, pos, oc), oc in low bits ->
// the 4 quad reads are lane-consecutive (coalesced). Quad order unchanged.
// pc: fp32 [b*TC+tl][oc*9+pos] (unchanged layout for conv3).
// ---------------------------------------------------------------------------
__global__ __launch_bounds__(256) void k_lif2pool(const float* __restrict__ psp2c,
                                                  float* __restrict__ pc,
                                                  float* __restrict__ st2,
                                                  int TC, int first) {
    int idx = blockIdx.x * 256 + threadIdx.x;   // 73728
    int oc = idx & 127;
    int r = idx >> 7;                           // b*9 + pos
    int pos = r % 9;
    int b = r / 9;
    int py = pos / 3, px = pos - py * 3;
    const float* pb = psp2c + (size_t)b * TC * 4608;
    int off00 = ((2 * py) * 6 + 2 * px) * 128 + oc;
    int off01 = ((2 * py) * 6 + 2 * px + 1) * 128 + oc;
    int off10 = ((2 * py + 1) * 6 + 2 * px) * 128 + oc;
    int off11 = ((2 * py + 1) * 6 + 2 * px + 1) * 128 + oc;
    float* pd = pc + (size_t)b * TC * 1152 + oc * 9 + pos;
    float c0, c1, c2, c3, v0, v1, v2, v3, s0, s1, s2, s3;
    if (first) {
        c0 = c1 = c2 = c3 = v0 = v1 = v2 = v3 = s0 = s1 = s2 = s3 = 0.f;
    } else {
        c0 = st2[idx];              c1 = st2[73728 + idx];
        c2 = st2[147456 + idx];     c3 = st2[221184 + idx];
        v0 = st2[294912 + idx];     v1 = st2[368640 + idx];
        v2 = st2[442368 + idx];     v3 = st2[516096 + idx];
        s0 = st2[589824 + idx];     s1 = st2[663552 + idx];
        s2 = st2[737280 + idx];     s3 = st2[811008 + idx];
    }
    for (int tl = 0; tl < TC; tl++) {
        const float* pt = pb + (size_t)tl * 4608;
        float p0 = pt[off00];
        float p1 = pt[off01];
        float p2 = pt[off10];
        float p3 = pt[off11];
        lif32(p0, c0, v0, s0);
        lif32(p1, c1, v1, s1);
        lif32(p2, c2, v2, s2);
        lif32(p3, c3, v3, s3);
        // sum of 0/1 values: exact in any order; *0.25 exact
        pd[(size_t)tl * 1152] = __fmul_rn(0.25f, __fadd_rn(__fadd_rn(__fadd_rn(s0, s1), s2), s3));
    }
    st2[idx] = c0;           st2[73728 + idx] = c1;
    st2[147456 + idx] = c2;  st2[221184 + idx] = c3;
    st2[294912 + idx] = v0;  st2[368640 + idx] = v1;
    st2[442368 + idx] = v2;  st2[516096 + idx] = v3;
    st2[589824 + idx] = s0;  st2[663552 + idx] = s1;
    st2[737280 + idx] = s2;  st2[811008 + idx] = s3;
}

// ---------------------------------------------------------------------------
// K4: conv3 GEMM, 4 rows x 256 outputs per block. Per output: sequential
// fp32 fmaf k=0..1151 ascending. Epilogue: +bias unfused.
// ---------------------------------------------------------------------------
__global__ __launch_bounds__(256) void k_conv3(const float* __restrict__ pc,
                                               const float* __restrict__ w3T,
                                               const float* __restrict__ b3,
                                               float* __restrict__ psp3c) {
    __shared__ float a_s[4 * 1152];
    int row0 = blockIdx.x * 4;
    int tid = threadIdx.x;
    int oq = tid & 63, mg = tid >> 6;           // 64 output-quads x 4 rows
    for (int idx = tid; idx < 4 * 1152; idx += 256) {
        int m = idx / 1152, k = idx - m * 1152;
        a_s[idx] = pc[(size_t)(row0 + m) * 1152 + k];
    }
    __syncthreads();
    float acc[4] = {0.f, 0.f, 0.f, 0.f};
    const float* as_row = &a_s[mg * 1152];      // wave-uniform -> broadcast reads
#pragma unroll 4
    for (int k = 0; k < 1152; k++) {
        float4 wv = *(const float4*)&w3T[(size_t)k * 256 + (oq << 2)];
        float am = as_row[k];
        acc[0] = fmaf(wv.x, am, acc[0]);
        acc[1] = fmaf(wv.y, am, acc[1]);
        acc[2] = fmaf(wv.z, am, acc[2]);
        acc[3] = fmaf(wv.w, am, acc[3]);
    }
    float* dst = psp3c + (size_t)(row0 + mg) * 256 + (oq << 2);
#pragma unroll
    for (int oo = 0; oo < 4; oo++)
        dst[oo] = __fadd_rn(acc[oo], b3[(oq << 2) + oo]);
}

// ---------------------------------------------------------------------------
// K5: LIF3 scan on chunk, fp32 states (st3), writes u8 s3u8[b][t][256].
// ---------------------------------------------------------------------------
__global__ __launch_bounds__(256) void k_scan3(const float* __restrict__ psp3c,
                                               unsigned char* __restrict__ s3u8,
                                               float* __restrict__ st3,
                                               int t0, int TC, int first) {
    int idx = blockIdx.x * 256 + threadIdx.x;   // 16384
    int b = idx >> 8, n = idx & 255;
    float cur, volt, spk;
    if (first) { cur = 0.f; volt = 0.f; spk = 0.f; }
    else { cur = st3[idx]; volt = st3[16384 + idx]; spk = st3[32768 + idx]; }
    for (int tl = 0; tl < TC; tl++) {
        lif32(psp3c[(size_t)(b * TC + tl) * 256 + n], cur, volt, spk);
        s3u8[((size_t)b * T_ + t0 + tl) * 256 + n] = (unsigned char)spk;
    }
    st3[idx] = cur; st3[16384 + idx] = volt; st3[32768 + idx] = spk;
}

// ---------------------------------------------------------------------------
// K6: temporal conv, back-end chunk TCB=50. Per tap: sequential fp32 dot
// (k=0..255) -> +bias (unfused) -> gated sequential psum (numpy order).
// ---------------------------------------------------------------------------
__global__ __launch_bounds__(256) void k_tc(const unsigned char* __restrict__ s3u8,
                                            const float* __restrict__ tcT,
                                            const float* __restrict__ tc_b,
                                            float* __restrict__ ptcc, int t0) {
    __shared__ float a_s[16 * 256];
    int crow0 = blockIdx.x * 16;
    int tid = threadIdx.x;
    int oq = tid & 63, mg = tid >> 6;
    float psum[4][4];
#pragma unroll
    for (int oo = 0; oo < 4; oo++)
#pragma unroll
        for (int mi = 0; mi < 4; mi++) psum[oo][mi] = 0.f;
    for (int tap = 0; tap < 3; tap++) {
        __syncthreads();
        for (int idx = tid; idx < 16 * 256; idx += 256) {
            int m = idx >> 8, k = idx & 255;
            int crow = crow0 + m;
            int b = crow / TCB_, tl = crow - b * TCB_;
            int t = t0 + tl;
            float v = 0.f;
            if (t >= tap) v = (float)s3u8[((size_t)b * T_ + t - tap) * 256 + k];
            a_s[idx] = v;
        }
        __syncthreads();
        float acc[4][4];
#pragma unroll
        for (int oo = 0; oo < 4; oo++)
#pragma unroll
            for (int mi = 0; mi < 4; mi++) acc[oo][mi] = 0.f;
        const float* wbase = tcT + (size_t)tap * 65536 + (oq << 2);
        for (int k = 0; k < 256; k++) {
            float4 wv = *(const float4*)(wbase + (size_t)k * 256);
            float w4[4] = {wv.x, wv.y, wv.z, wv.w};
            float am[4];
#pragma unroll
            for (int mi = 0; mi < 4; mi++) am[mi] = a_s[(mg * 4 + mi) * 256 + k];
#pragma unroll
            for (int oo = 0; oo < 4; oo++)
#pragma unroll
                for (int mi = 0; mi < 4; mi++)
                    acc[oo][mi] = fmaf(w4[oo], am[mi], acc[oo][mi]);
        }
#pragma unroll
        for (int mi = 0; mi < 4; mi++) {
            int crow = crow0 + mg * 4 + mi;
            int b = crow / TCB_, tl = crow - b * TCB_;
            int t = t0 + tl;
            float g = (t >= tap) ? 1.0f : 0.0f;
#pragma unroll
            for (int oo = 0; oo < 4; oo++) {
                int oc = (oq << 2) + oo;
                float tap_f = __fadd_rn(acc[oo][mi], tc_b[tap * 256 + oc]);
                psum[oo][mi] = __fadd_rn(psum[oo][mi], __fmul_rn(g, tap_f));
            }
        }
    }
#pragma unroll
    for (int mi = 0; mi < 4; mi++) {
        int crow = crow0 + mg * 4 + mi;
        float* dst = ptcc + (size_t)crow * 256 + (oq << 2);
#pragma unroll
        for (int oo = 0; oo < 4; oo++) dst[oo] = psum[oo][mi];
    }
}

// ---------------------------------------------------------------------------
// K7: LIF scan for tc layer, back-end chunk, fp32 states st_tc.
// ---------------------------------------------------------------------------
__global__ __launch_bounds__(256) void k_scan_tc(const float* __restrict__ ptcc,
                                                 unsigned char* __restrict__ s_tc8,
                                                 float* __restrict__ st_tc,
                                                 int t0, int first) {
    int idx = blockIdx.x * 256 + threadIdx.x;   // 16384
    int b = idx >> 8, n = idx & 255;
    float cur, volt, spk;
    if (first) { cur = 0.f; volt = 0.f; spk = 0.f; }
    else { cur = st_tc[idx]; volt = st_tc[16384 + idx]; spk = st_tc[32768 + idx]; }
    for (int tl = 0; tl < TCB_; tl++) {
        lif32(ptcc[(size_t)(b * TCB_ + tl) * 256 + n], cur, volt, spk);
        s_tc8[((size_t)b * T_ + t0 + tl) * 256 + n] = (unsigned char)spk;
    }
    st_tc[idx] = cur; st_tc[16384 + idx] = volt; st_tc[32768 + idx] = spk;
}

// ---------------------------------------------------------------------------
// K8: recurrent layer, split-chain, NAMED-float4 register weights +
// amdgpu_waves_per_eu(2,2) (R16 exact — measured 264us best).
// 512 threads/block, WG per batch element. Thread (o = tid&255,
// half = tid>>8) holds its 128-weight slice in 32 NAMED float4 variables.
// Per step:
//   half 0: acc = chain(0, k=0..127)          -> acc_s[o]
//   barrier
//   half 1: acc = chain(acc_s[o], k=128..255) -> +stc +rb -> LIF -> store,
//           publish spike to spk_s[p^1]
//   barrier
// chain(chain(0,k<128),k>=128) is the IDENTICAL fmaf sequence as the single
// 256-link chain -> bit-identical. fmaf(s,w,acc) with s in {0,1} is
// bit-identical to __fadd_rn(acc, s?w:0). Branches wave-uniform.
// ---------------------------------------------------------------------------
__global__ __launch_bounds__(512)
__attribute__((amdgpu_waves_per_eu(2, 2)))
void k_rec(const unsigned char* __restrict__ s_tc8,
           const float* __restrict__ rec_w,
           const float* __restrict__ rec_b,
           unsigned char* __restrict__ s_r8) {
    __shared__ __align__(16) float spk_s[2][256];
    __shared__ float acc_s[256];
    int b = blockIdx.x;
    int tid = threadIdx.x;
    int o = tid & 255, half = tid >> 8;
    const float* wrow = rec_w + (size_t)o * 256 + (half << 7);
#define WD(i) float4 w##i = *(const float4*)&wrow[4 * i];
    WD(0)  WD(1)  WD(2)  WD(3)  WD(4)  WD(5)  WD(6)  WD(7)
    WD(8)  WD(9)  WD(10) WD(11) WD(12) WD(13) WD(14) WD(15)
    WD(16) WD(17) WD(18) WD(19) WD(20) WD(21) WD(22) WD(23)
    WD(24) WD(25) WD(26) WD(27) WD(28) WD(29) WD(30) WD(31)
#undef WD
    if (half == 0) spk_s[0][o] = 0.f;
    float cur = 0.f, volt = 0.f, spk = 0.f;
    float rb = rec_b[o];
    const unsigned char* stp = s_tc8 + (size_t)b * T_ * 256 + o;
    unsigned char* srp = s_r8 + (size_t)b * T_ * 256 + o;
    __syncthreads();
    int p = 0;
    // CH(i): 4 chain links using float4 i (ascending k within the slice)
#define CH(i, sp) { float4 sv = *(const float4*)&(sp)[4 * i]; \
        acc = fmaf(sv.x, w##i.x, acc); acc = fmaf(sv.y, w##i.y, acc); \
        acc = fmaf(sv.z, w##i.z, acc); acc = fmaf(sv.w, w##i.w, acc); }
#define CHAIN32(sp) \
    CH(0,sp)  CH(1,sp)  CH(2,sp)  CH(3,sp)  CH(4,sp)  CH(5,sp)  CH(6,sp)  CH(7,sp) \
    CH(8,sp)  CH(9,sp)  CH(10,sp) CH(11,sp) CH(12,sp) CH(13,sp) CH(14,sp) CH(15,sp) \
    CH(16,sp) CH(17,sp) CH(18,sp) CH(19,sp) CH(20,sp) CH(21,sp) CH(22,sp) CH(23,sp) \
    CH(24,sp) CH(25,sp) CH(26,sp) CH(27,sp) CH(28,sp) CH(29,sp) CH(30,sp) CH(31,sp)
    for (int t = 0; t < T_; t++) {
        if (half == 0) {
            const float* sp = spk_s[p];
            float acc = 0.f;
            CHAIN32(sp)
            acc_s[o] = acc;
        }
        __syncthreads();                // publish partial acc
        if (half == 1) {
            float stc = (float)stp[(size_t)t * 256];   // independent, issues early
            const float* sp = spk_s[p] + 128;
            float acc = acc_s[o];
            CHAIN32(sp)
            float psp = __fadd_rn(__fadd_rn(stc, acc), rb);
            lif32(psp, cur, volt, spk);
            srp[(size_t)t * 256] = (unsigned char)spk;
            spk_s[p ^ 1][o] = spk;      // publish spike for next step
        }
        __syncthreads();
        p ^= 1;
    }
#undef CH
#undef CHAIN32
}

// ---------------------------------------------------------------------------
// K9: fc1 GEMM, back-end chunk. Sequential fp32 fmaf k=0..255; +bias after.
// ---------------------------------------------------------------------------
__global__ __launch_bounds__(256) void k_fc1(const unsigned char* __restrict__ s_r8,
                                             const float* __restrict__ fc1T,
                                             const float* __restrict__ fc1_b,
                                             float* __restrict__ pfc, int t0) {
    __shared__ float a_s[16 * 256];
    int crow0 = blockIdx.x * 16;
    int tid = threadIdx.x;
    int oq = tid & 31, mg = tid >> 5;           // 8 m-groups, tile 2m
    float acc[4][2];
#pragma unroll
    for (int oo = 0; oo < 4; oo++) { acc[oo][0] = 0.f; acc[oo][1] = 0.f; }
    for (int idx = tid; idx < 16 * 256; idx += 256) {
        int m = idx >> 8, k = idx & 255;
        int crow = crow0 + m;
        int b = crow / TCB_, tl = crow - b * TCB_;
        a_s[idx] = (float)s_r8[((size_t)b * T_ + t0 + tl) * 256 + k];
    }
    __syncthreads();
    for (int k = 0; k < 256; k++) {
        float4 wv = *(const float4*)&fc1T[(size_t)k * 128 + (oq << 2)];
        float w4[4] = {wv.x, wv.y, wv.z, wv.w};
        float a0 = a_s[(mg * 2 + 0) * 256 + k];
        float a1 = a_s[(mg * 2 + 1) * 256 + k];
#pragma unroll
        for (int oo = 0; oo < 4; oo++) {
            acc[oo][0] = fmaf(w4[oo], a0, acc[oo][0]);
            acc[oo][1] = fmaf(w4[oo], a1, acc[oo][1]);
        }
    }
#pragma unroll
    for (int mi = 0; mi < 2; mi++) {
        float* dst = pfc + (size_t)(crow0 + mg * 2 + mi) * 128 + (oq << 2);
#pragma unroll
        for (int oo = 0; oo < 4; oo++)
            dst[oo] = __fadd_rn(acc[oo][mi], fc1_b[(oq << 2) + oo]);
    }
}

// ---------------------------------------------------------------------------
// K10: LIF scan for fc1 layer, back-end chunk, fp32 states st_f.
// ---------------------------------------------------------------------------
__global__ __launch_bounds__(256) void k_scan_f(const float* __restrict__ pfc,
                                                unsigned char* __restrict__ s_f8,
                                                float* __restrict__ st_f,
                                                int t0, int first) {
    int idx = blockIdx.x * 256 + threadIdx.x;   // 8192
    int b = idx >> 7, n = idx & 127;
    float cur, volt, spk;
    if (first) { cur = 0.f; volt = 0.f; spk = 0.f; }
    else { cur = st_f[idx]; volt = st_f[8192 + idx]; spk = st_f[16384 + idx]; }
    for (int tl = 0; tl < TCB_; tl++) {
        lif32(pfc[(size_t)(b * TCB_ + tl) * 128 + n], cur, volt, spk);
        s_f8[((size_t)b * T_ + t0 + tl) * 128 + n] = (unsigned char)spk;
    }
    st_f[idx] = cur; st_f[8192 + idx] = volt; st_f[16384 + idx] = spk;
}

// ---------------------------------------------------------------------------
// K11: out[b,:] = fc2_w @ (sum_t ts[t]*s_f[b,t,:]) — linear head, fp64
// accumulation (differences ~1e-7 are far below the bf16 floor).
// ---------------------------------------------------------------------------
__global__ __launch_bounds__(128) void k_final(const unsigned char* __restrict__ s_f8,
                                               const float* __restrict__ ts,
                                               const float* __restrict__ fc2,
                                               float* __restrict__ out) {
    __shared__ double q_s[128];
    int b = blockIdx.x, k = threadIdx.x;
    double q = 0.0;
    const unsigned char* sf = s_f8 + (size_t)b * T_ * 128 + k;
    for (int t = 0; t < T_; t++) q = fma((double)ts[t], (double)sf[(size_t)t * 128], q);
    q_s[k] = q;
    __syncthreads();
    if (k < 2) {
        double o = 0.0;
        for (int kk = 0; kk < 128; kk++) o = fma((double)fc2[k * 128 + kk], q_s[kk], o);
        out[b * 2 + k] = (float)o;
    }
}

// ---------------------------------------------------------------------------
extern "C" void kernel_launch(void* const* d_in, const int* in_sizes, int n_in,
                              void* d_out, int out_size, void* d_ws, size_t ws_size,
                              hipStream_t stream) {
    const float* x       = (const float*)d_in[0];
    const float* conv1_w = (const float*)d_in[1];
    const float* conv1_b = (const float*)d_in[2];
    const float* conv2_w = (const float*)d_in[3];
    const float* conv2_b = (const float*)d_in[4];
    const float* conv3_w = (const float*)d_in[5];
    const float* conv3_b = (const float*)d_in[6];
    const float* tc_w    = (const float*)d_in[7];
    const float* tc_b    = (const float*)d_in[8];
    const float* rec_w   = (const float*)d_in[9];
    const float* rec_b   = (const float*)d_in[10];
    const float* fc1_w   = (const float*)d_in[11];
    const float* fc1_b   = (const float*)d_in[12];
    const float* fc2_w   = (const float*)d_in[13];
    const float* ts_w    = (const float*)d_in[14];
    float* out = (float*)d_out;
    (void)in_sizes; (void)n_in; (void)out_size;

    // ---- persistent region: 21,299,200 B ----
    char* base = (char*)d_ws;
    float* w2T  = (float*)(base + 0);           //   294,912 B
    float* w3T  = (float*)(base + 294912);      // 1,179,648 B
    float* tcT  = (float*)(base + 1474560);     //   786,432 B
    float* recT = (float*)(base + 2260992);     //   262,144 B (unused)
    float* fc1T = (float*)(base + 2523136);     //   131,072 B
    float* st1  = (float*)(base + 2654208);     // 3,145,728 B
    float* st2  = (float*)(base + 5799936);     // 3,538,944 B
    float* st3  = (float*)(base + 9338880);     //   196,608 B
    float* st_tc= (float*)(base + 9535488);     //   196,608 B
    float* st_f = (float*)(base + 9732096);     //    98,304 B
    unsigned char* s3u8  = (unsigned char*)(base + 9830400);   // 3,276,800 B
    unsigned char* s_tc8 = (unsigned char*)(base + 13107200);  // 3,276,800 B
    unsigned char* s_r8  = (unsigned char*)(base + 16384000);  // 3,276,800 B
    unsigned char* s_f8  = (unsigned char*)(base + 19660800);  // 1,638,400 B

    // ---- chunked scratch region, TCF chosen from ws_size (graph-safe) ----
    const size_t PERS = 21299200;
    const size_t PER_T = 1802240;   // bytes per front-end timestep (B=64)
    int TCF;
    if      (ws_size >= PERS + 40 * PER_T) TCF = 40;
    else if (ws_size >= PERS + 20 * PER_T) TCF = 20;
    else if (ws_size >= PERS +  8 * PER_T) TCF = 8;   // 35.7 MB — proven fit
    else                                   TCF = 4;
    int NCH = T_ / TCF;
    char* cb = base + PERS;
    float* psp2c = (float*)(cb);                                      // TCF*1,179,648 B
    float* psp3c = (float*)(cb + (size_t)TCF * 1179648);              // TCF*65,536 B
    float* pc    = (float*)(cb + (size_t)TCF * (1179648 + 65536));    // TCF*294,912 B
    unsigned char* s1c = (unsigned char*)(cb + (size_t)TCF * (1179648 + 65536 + 294912)); // TCF*262,144 B
    // back-end chunk buffers alias the front-end scratch (dead by then)
    float* ptcc = (float*)(cb);              // 3,276,800 B
    float* pfc  = (float*)(cb + 3276800);    // 1,638,400 B

    k_setup<<<2592, 256, 0, stream>>>(conv2_w, conv3_w, tc_w, rec_w, fc1_w,
                                      w2T, w3T, tcT, recT, fc1T);
    for (int ch = 0; ch < NCH; ch++) {
        int t0 = ch * TCF;
        int first = (ch == 0) ? 1 : 0;
        k_conv1<<<1024, 256, 0, stream>>>(x, conv1_w, conv1_b, s1c, st1, t0, TCF, first);
        k_conv2<<<B_ * TCF, 128, 0, stream>>>(s1c, w2T, conv2_b, psp2c, TCF);
        k_lif2pool<<<288, 256, 0, stream>>>(psp2c, pc, st2, TCF, first);
        k_conv3<<<B_ * TCF / 4, 256, 0, stream>>>(pc, w3T, conv3_b, psp3c);
        k_scan3<<<64, 256, 0, stream>>>(psp3c, s3u8, st3, t0, TCF, first);
    }
    for (int bc = 0; bc < T_ / TCB_; bc++) {
        int t0 = bc * TCB_;
        k_tc<<<B_ * TCB_ / 16, 256, 0, stream>>>(s3u8, tcT, tc_b, ptcc, t0);
        k_scan_tc<<<64, 256, 0, stream>>>(ptcc, s_tc8, st_tc, t0, (bc == 0) ? 1 : 0);
    }
    k_rec<<<64, 512, 0, stream>>>(s_tc8, rec_w, rec_b, s_r8);
    for (int bc = 0; bc < T_ / TCB_; bc++) {
        int t0 = bc * TCB_;
        k_fc1<<<B_ * TCB_ / 16, 256, 0, stream>>>(s_r8, fc1T, fc1_b, pfc, t0);
        k_scan_f<<<32, 256, 0, stream>>>(pfc, s_f8, st_f, t0, (bc == 0) ? 1 : 0);
    }
    k_final<<<64, 128, 0, stream>>>(s_f8, ts_w, fc2_w, out);
}